// Round 9
// baseline (64.686 us; speedup 1.0000x reference)
//
#include <hip/hip_runtime.h>

#define C_NUM   256
#define K_CODES 4096
#define D_CB    8
#define THREADS 512
#define TPW     8                   // tuples per wave
#define CHUNKS  16                  // per wave: 2048 codes / 128 per chunk (2 per lane)

__device__ __forceinline__ float rfl(float v) {
    return __int_as_float(__builtin_amdgcn_readfirstlane(__float_as_int(v)));
}

__global__ __launch_bounds__(THREADS, 2)   // min-waves=2: higher values wreck the allocator (R3/R4/R7)
void dkvb_kernel(const float* __restrict__ emb,
                 const float* __restrict__ keys,
                 const float* __restrict__ values,
                 float* __restrict__ out) {
    __shared__ float xs[32][D_CB];   // 1 KB
    __shared__ float dL[8][TPW];
    __shared__ int   iL[8][TPW];

    const int bid  = blockIdx.x;
    const int c    = bid & 255;      // codebook (4 blocks/codebook, same XCD: 256%8==0)
    const int q    = bid >> 8;       // tuple quarter
    const int tid  = threadIdx.x;
    const int wave = tid >> 6;
    const int lane = tid & 63;
    const int s    = wave & 3;       // tuple slice (8 tuples)
    const int g    = wave >> 2;      // code half: 0 -> 0..2047, 1 -> 2048..4095

    // ---- stage this block's 32 tuples of x into LDS ----
    if (tid < 256) {
        const int tl = tid >> 3, j = tid & 7;
        const int tg = q * 32 + tl;
        xs[tl][j] = emb[(size_t)(tg >> 4) * 32768 + c * 128 + j * 16 + (tg & 15)];
    }
    __syncthreads();

    // ---- x' = -2*x into SGPRs (wave-uniform, exact scale) ----
    float x[TPW][8];
    #pragma unroll
    for (int t = 0; t < TPW; ++t) {
        #pragma unroll
        for (int j = 0; j < 8; ++j) x[t][j] = rfl(-2.0f * xs[s * TPW + t][j]);
    }

    float bestd[TPW];
    int   besti[TPW];
    #pragma unroll
    for (int t = 0; t < TPW; ++t) { bestd[t] = 3.4028235e38f; besti[t] = 0; }

    // ---- scan this half's 2048 codes, 128/chunk (lane owns codes lane and lane+64) ----
    const float4* kb = (const float4*)(keys + (size_t)c * K_CODES * D_CB);
    const int basef4 = g * 4096;          // float4 index of code-half base
    const int o0 = basef4 + lane * 2;     // code lane       of chunk
    const int o1 = basef4 + 128 + lane * 2; // code lane+64  of chunk
    float4 a0 = kb[o0];
    float4 a1 = kb[o0 + 1];
    float4 a2 = kb[o1];
    float4 a3 = kb[o1 + 1];
    for (int ch = 0; ch < CHUNKS; ++ch) {
        const int nco = ((ch + 1 < CHUNKS) ? (ch + 1) : ch) * 256;
        const float4 b0 = kb[nco + o0];
        const float4 b1 = kb[nco + o0 + 1];
        const float4 b2 = kb[nco + o1];
        const float4 b3 = kb[nco + o1 + 1];

        const int codeA = g * 2048 + ch * 128 + lane;   // codeB = codeA + 64
        float k2a = a0.x * a0.x;
        k2a = fmaf(a0.y, a0.y, k2a);
        k2a = fmaf(a0.z, a0.z, k2a);
        k2a = fmaf(a0.w, a0.w, k2a);
        k2a = fmaf(a1.x, a1.x, k2a);
        k2a = fmaf(a1.y, a1.y, k2a);
        k2a = fmaf(a1.z, a1.z, k2a);
        k2a = fmaf(a1.w, a1.w, k2a);
        float k2b = a2.x * a2.x;
        k2b = fmaf(a2.y, a2.y, k2b);
        k2b = fmaf(a2.z, a2.z, k2b);
        k2b = fmaf(a2.w, a2.w, k2b);
        k2b = fmaf(a3.x, a3.x, k2b);
        k2b = fmaf(a3.y, a3.y, k2b);
        k2b = fmaf(a3.z, a3.z, k2b);
        k2b = fmaf(a3.w, a3.w, k2b);

        #pragma unroll
        for (int t = 0; t < TPW; ++t) {
            float dA = fmaf(x[t][0], a0.x, k2a);
            dA = fmaf(x[t][1], a0.y, dA);
            dA = fmaf(x[t][2], a0.z, dA);
            dA = fmaf(x[t][3], a0.w, dA);
            dA = fmaf(x[t][4], a1.x, dA);
            dA = fmaf(x[t][5], a1.y, dA);
            dA = fmaf(x[t][6], a1.z, dA);
            dA = fmaf(x[t][7], a1.w, dA);
            const bool ltA = dA < bestd[t];
            bestd[t] = ltA ? dA : bestd[t];
            besti[t] = ltA ? codeA : besti[t];

            float dB = fmaf(x[t][0], a2.x, k2b);
            dB = fmaf(x[t][1], a2.y, dB);
            dB = fmaf(x[t][2], a2.z, dB);
            dB = fmaf(x[t][3], a2.w, dB);
            dB = fmaf(x[t][4], a3.x, dB);
            dB = fmaf(x[t][5], a3.y, dB);
            dB = fmaf(x[t][6], a3.z, dB);
            dB = fmaf(x[t][7], a3.w, dB);
            const bool ltB = dB < bestd[t];
            bestd[t] = ltB ? dB : bestd[t];
            besti[t] = ltB ? (codeA + 64) : besti[t];
        }
        a0 = b0; a1 = b1; a2 = b2; a3 = b3;
    }

    // ---- cross-lane argmin per tuple (tie -> smaller index == numpy) ----
    float myd = 0.0f;
    int   myidx = 0;
    #pragma unroll
    for (int t = 0; t < TPW; ++t) {
        float d = bestd[t];
        int   i = besti[t];
        #pragma unroll
        for (int m = 32; m >= 1; m >>= 1) {
            const float od = __shfl_xor(d, m, 64);
            const int   oi = __shfl_xor(i, m, 64);
            if (od < d || (od == d && oi < i)) { d = od; i = oi; }
        }
        if (lane == t) { myd = d; myidx = i; }
    }

    // ---- cross-group combine via LDS ----
    if (lane < TPW) { dL[wave][lane] = myd; iL[wave][lane] = myidx; }
    __syncthreads();

    if (g == 0 && lane < TPW) {
        const float d0 = dL[wave][lane];
        const float d1 = dL[wave + 4][lane];
        // group 1 codes all larger; exact tie keeps group 0 (numpy tie-break)
        const int idx = (d1 < d0) ? iL[wave + 4][lane] : iL[wave][lane];

        const int tg = q * 32 + s * TPW + lane;   // tuple = b*16 + n
        const int b = tg >> 4, n = tg & 15;
        const float4* vr = (const float4*)(values + ((size_t)c * K_CODES + idx) * D_CB);
        const float4 v0 = vr[0];
        const float4 v1 = vr[1];
        float* op = out + (size_t)b * 32768 + c * 128 + n;
        op[0]   = v0.x; op[16]  = v0.y; op[32]  = v0.z; op[48]  = v0.w;
        op[64]  = v1.x; op[80]  = v1.y; op[96]  = v1.z; op[112] = v1.w;
    }
}

extern "C" void kernel_launch(void* const* d_in, const int* in_sizes, int n_in,
                              void* d_out, int out_size, void* d_ws, size_t ws_size,
                              hipStream_t stream) {
    const float* emb    = (const float*)d_in[0];
    const float* keys   = (const float*)d_in[1];
    const float* values = (const float*)d_in[2];
    float* out = (float*)d_out;
    dkvb_kernel<<<4 * C_NUM, THREADS, 0, stream>>>(emb, keys, values, out);
}

// Round 10
// 47.438 us; speedup vs baseline: 1.3636x; 1.3636x over previous
//
#include <hip/hip_runtime.h>

#define C_NUM   256
#define K_CODES 4096
#define D_CB    8
#define THREADS 512
#define TPW     8                   // tuples per wave; 8 waves x 8 = 64 tuples/block
#define CHUNKS  64                  // every wave scans all 4096 codes, 64/chunk

__device__ __forceinline__ float rfl(float v) {
    return __int_as_float(__builtin_amdgcn_readfirstlane(__float_as_int(v)));
}

__global__ __launch_bounds__(THREADS, 2)   // min-waves=2; larger values wreck the allocator (R3/R4/R7)
void dkvb_kernel(const float* __restrict__ emb,
                 const float* __restrict__ keys,
                 const float* __restrict__ values,
                 float* __restrict__ out) {
    __shared__ float xs[64][D_CB];   // 2 KB

    const int bid  = blockIdx.x;
    const int c    = bid & 255;      // codebook; bid and bid+256 share an XCD (256%8==0)
    const int h    = bid >> 8;       // tuple half: 0 -> tuples 0..63, 1 -> 64..127
    const int tid  = threadIdx.x;
    const int wave = tid >> 6;
    const int lane = tid & 63;

    // ---- stage this block's 64 tuples of x into LDS (one element/thread) ----
    // x[t][j] = emb[(t>>4)*32768 + c*128 + j*16 + (t&15)]
    {
        const int tl = tid >> 3, j = tid & 7;
        const int tg = h * 64 + tl;
        xs[tl][j] = emb[(size_t)(tg >> 4) * 32768 + c * 128 + j * 16 + (tg & 15)];
    }
    __syncthreads();

    // ---- x' = -2*x into SGPRs (wave-uniform, exact scale) ----
    float x[TPW][8];
    #pragma unroll
    for (int t = 0; t < TPW; ++t) {
        #pragma unroll
        for (int j = 0; j < 8; ++j) x[t][j] = rfl(-2.0f * xs[wave * TPW + t][j]);
    }

    float bestd[TPW];
    int   besti[TPW];
    #pragma unroll
    for (int t = 0; t < TPW; ++t) { bestd[t] = 3.4028235e38f; besti[t] = 0; }

    // ---- all 8 waves scan the SAME code stream in lockstep (L1 reuse) ----
    // dist' = k2 + sum x'_j k_j   (argmin-equivalent to full distance)
    const float4* kb = (const float4*)(keys + (size_t)c * K_CODES * D_CB);
    float4 a0 = kb[lane * 2];
    float4 a1 = kb[lane * 2 + 1];
    for (int ch = 0; ch < CHUNKS; ++ch) {
        const int nco = ((ch + 1 < CHUNKS) ? (ch + 1) : ch) * 128;
        const float4 b0 = kb[nco + lane * 2];
        const float4 b1 = kb[nco + lane * 2 + 1];

        const int code = ch * 64 + lane;
        float k2 = a0.x * a0.x;
        k2 = fmaf(a0.y, a0.y, k2);
        k2 = fmaf(a0.z, a0.z, k2);
        k2 = fmaf(a0.w, a0.w, k2);
        k2 = fmaf(a1.x, a1.x, k2);
        k2 = fmaf(a1.y, a1.y, k2);
        k2 = fmaf(a1.z, a1.z, k2);
        k2 = fmaf(a1.w, a1.w, k2);

        #pragma unroll
        for (int t = 0; t < TPW; ++t) {
            float dist = fmaf(x[t][0], a0.x, k2);
            dist = fmaf(x[t][1], a0.y, dist);
            dist = fmaf(x[t][2], a0.z, dist);
            dist = fmaf(x[t][3], a0.w, dist);
            dist = fmaf(x[t][4], a1.x, dist);
            dist = fmaf(x[t][5], a1.y, dist);
            dist = fmaf(x[t][6], a1.z, dist);
            dist = fmaf(x[t][7], a1.w, dist);
            const bool lt = dist < bestd[t];
            bestd[t] = lt ? dist : bestd[t];
            besti[t] = lt ? code : besti[t];
        }
        a0 = b0; a1 = b1;

        // keep the 8 waves within one L1 window (8 KB per 4 chunks).
        // raw s_barrier: purely temporal, no waitcnt -> prefetch stays in flight.
        if ((ch & 3) == 3) __builtin_amdgcn_s_barrier();
    }

    // ---- cross-lane argmin per tuple (tie -> smaller index == numpy) ----
    int myidx = 0;
    #pragma unroll
    for (int t = 0; t < TPW; ++t) {
        float d = bestd[t];
        int   i = besti[t];
        #pragma unroll
        for (int m = 32; m >= 1; m >>= 1) {
            const float od = __shfl_xor(d, m, 64);
            const int   oi = __shfl_xor(i, m, 64);
            if (od < d || (od == d && oi < i)) { d = od; i = oi; }
        }
        if (lane == t) myidx = i;
    }

    // ---- gather values row + scatter to output ----
    if (lane < TPW) {
        const int tg = h * 64 + wave * TPW + lane;   // tuple = b*16 + n
        const int b = tg >> 4, n = tg & 15;
        const float4* vr = (const float4*)(values + ((size_t)c * K_CODES + myidx) * D_CB);
        const float4 v0 = vr[0];
        const float4 v1 = vr[1];
        float* op = out + (size_t)b * 32768 + c * 128 + n;
        op[0]   = v0.x; op[16]  = v0.y; op[32]  = v0.z; op[48]  = v0.w;
        op[64]  = v1.x; op[80]  = v1.y; op[96]  = v1.z; op[112] = v1.w;
    }
}

extern "C" void kernel_launch(void* const* d_in, const int* in_sizes, int n_in,
                              void* d_out, int out_size, void* d_ws, size_t ws_size,
                              hipStream_t stream) {
    const float* emb    = (const float*)d_in[0];
    const float* keys   = (const float*)d_in[1];
    const float* values = (const float*)d_in[2];
    float* out = (float*)d_out;
    dkvb_kernel<<<2 * C_NUM, THREADS, 0, stream>>>(emb, keys, values, out);
}

// Round 11
// 45.101 us; speedup vs baseline: 1.4343x; 1.0518x over previous
//
#include <hip/hip_runtime.h>

#define C_NUM   256
#define K_CODES 4096
#define D_CB    8
#define THREADS 512
#define TPW     8                   // tuples per wave; 8 waves x 8 = 64 tuples/block
#define CHUNKS  64                  // every wave scans all 4096 codes, 64/chunk

typedef float v2f __attribute__((ext_vector_type(2)));

// packed fp32 FMA: d = x * bcast(key) + d, tuple-pair in the two halves.
// op_sel[i]/op_sel_hi[i] pick the src word for the low/high result half.
#define PK_INIT(d, x, kp, c) \
    asm("v_pk_fma_f32 %0, %1, %2, %3 op_sel:[0,0,0] op_sel_hi:[1,0,1]" \
        : "=v"(d) : "v"(x), "v"(kp), "v"(c))
#define PK_LO(d, x, kp) \
    asm("v_pk_fma_f32 %0, %1, %2, %0 op_sel:[0,0,0] op_sel_hi:[1,0,1]" \
        : "+v"(d) : "v"(x), "v"(kp))
#define PK_HI(d, x, kp) \
    asm("v_pk_fma_f32 %0, %1, %2, %0 op_sel:[0,1,0] op_sel_hi:[1,1,1]" \
        : "+v"(d) : "v"(x), "v"(kp))

__global__ __launch_bounds__(THREADS, 2)   // min-waves=2; larger values wreck the allocator (R3/R4/R7)
void dkvb_kernel(const float* __restrict__ emb,
                 const float* __restrict__ keys,
                 const float* __restrict__ values,
                 float* __restrict__ out) {
    __shared__ float xs[64][D_CB];   // 2 KB

    const int bid  = blockIdx.x;
    const int c    = bid & 255;      // codebook; bid and bid+256 share an XCD (256%8==0)
    const int h    = bid >> 8;       // tuple half: 0 -> tuples 0..63, 1 -> 64..127
    const int tid  = threadIdx.x;
    const int wave = tid >> 6;
    const int lane = tid & 63;

    // ---- stage this block's 64 tuples of x into LDS (one element/thread) ----
    // x[t][j] = emb[(t>>4)*32768 + c*128 + j*16 + (t&15)]
    {
        const int tl = tid >> 3, j = tid & 7;
        const int tg = h * 64 + tl;
        xs[tl][j] = emb[(size_t)(tg >> 4) * 32768 + c * 128 + j * 16 + (tg & 15)];
    }
    __syncthreads();

    // ---- x' = -2*x, tuple-PAIRED into VGPR float2s: xp[u][j] = (x'[2u][j], x'[2u+1][j]) ----
    v2f xp[4][8];
    #pragma unroll
    for (int u = 0; u < 4; ++u) {
        #pragma unroll
        for (int j = 0; j < 8; ++j) {
            v2f p;
            p.x = -2.0f * xs[wave * TPW + 2 * u][j];
            p.y = -2.0f * xs[wave * TPW + 2 * u + 1][j];
            xp[u][j] = p;
        }
    }

    float bestd[TPW];
    int   besti[TPW];
    #pragma unroll
    for (int t = 0; t < TPW; ++t) { bestd[t] = 3.4028235e38f; besti[t] = 0; }

    // ---- all 8 waves scan the SAME code stream in lockstep (L1 reuse) ----
    // dist' = k2 + sum x'_j k_j  (same serial chain per tuple as R10 -> identical rounding)
    const v2f* kb2 = (const v2f*)(keys + (size_t)c * K_CODES * D_CB);
    const int o = lane * 4;          // 4 float2 = one 8-float key row per lane
    v2f a0 = kb2[o], a1 = kb2[o + 1], a2 = kb2[o + 2], a3 = kb2[o + 3];
    for (int ch = 0; ch < CHUNKS; ++ch) {
        const int nco = ((ch + 1 < CHUNKS) ? (ch + 1) : ch) * 256 + o;
        const v2f b0 = kb2[nco];
        const v2f b1 = kb2[nco + 1];
        const v2f b2 = kb2[nco + 2];
        const v2f b3 = kb2[nco + 3];

        const int code = ch * 64 + lane;
        float k2 = a0.x * a0.x;
        k2 = fmaf(a0.y, a0.y, k2);
        k2 = fmaf(a1.x, a1.x, k2);
        k2 = fmaf(a1.y, a1.y, k2);
        k2 = fmaf(a2.x, a2.x, k2);
        k2 = fmaf(a2.y, a2.y, k2);
        k2 = fmaf(a3.x, a3.x, k2);
        k2 = fmaf(a3.y, a3.y, k2);
        v2f k2p; k2p.x = k2; k2p.y = k2;

        #pragma unroll
        for (int u = 0; u < 4; ++u) {
            v2f d;
            PK_INIT(d, xp[u][0], a0, k2p);   // d = x0'*k0 + k2 (both halves)
            PK_HI (d, xp[u][1], a0);
            PK_LO (d, xp[u][2], a1);
            PK_HI (d, xp[u][3], a1);
            PK_LO (d, xp[u][4], a2);
            PK_HI (d, xp[u][5], a2);
            PK_LO (d, xp[u][6], a3);
            PK_HI (d, xp[u][7], a3);

            const int t0 = 2 * u, t1 = 2 * u + 1;
            const bool lt0 = d.x < bestd[t0];
            bestd[t0] = lt0 ? d.x : bestd[t0];
            besti[t0] = lt0 ? code : besti[t0];
            const bool lt1 = d.y < bestd[t1];
            bestd[t1] = lt1 ? d.y : bestd[t1];
            besti[t1] = lt1 ? code : besti[t1];
        }
        a0 = b0; a1 = b1; a2 = b2; a3 = b3;

        // keep the 8 waves within one L1 window; raw s_barrier leaves prefetch in flight
        if ((ch & 3) == 3) __builtin_amdgcn_s_barrier();
    }

    // ---- cross-lane argmin per tuple (tie -> smaller index == numpy) ----
    int myidx = 0;
    #pragma unroll
    for (int t = 0; t < TPW; ++t) {
        float d = bestd[t];
        int   i = besti[t];
        #pragma unroll
        for (int m = 32; m >= 1; m >>= 1) {
            const float od = __shfl_xor(d, m, 64);
            const int   oi = __shfl_xor(i, m, 64);
            if (od < d || (od == d && oi < i)) { d = od; i = oi; }
        }
        if (lane == t) myidx = i;
    }

    // ---- gather values row + scatter to output ----
    if (lane < TPW) {
        const int tg = h * 64 + wave * TPW + lane;   // tuple = b*16 + n
        const int b = tg >> 4, n = tg & 15;
        const float4* vr = (const float4*)(values + ((size_t)c * K_CODES + myidx) * D_CB);
        const float4 v0 = vr[0];
        const float4 v1 = vr[1];
        float* op = out + (size_t)b * 32768 + c * 128 + n;
        op[0]   = v0.x; op[16]  = v0.y; op[32]  = v0.z; op[48]  = v0.w;
        op[64]  = v1.x; op[80]  = v1.y; op[96]  = v1.z; op[112] = v1.w;
    }
}

extern "C" void kernel_launch(void* const* d_in, const int* in_sizes, int n_in,
                              void* d_out, int out_size, void* d_ws, size_t ws_size,
                              hipStream_t stream) {
    const float* emb    = (const float*)d_in[0];
    const float* keys   = (const float*)d_in[1];
    const float* values = (const float*)d_in[2];
    float* out = (float*)d_out;
    dkvb_kernel<<<2 * C_NUM, THREADS, 0, stream>>>(emb, keys, values, out);
}